// Round 1
// baseline (804.523 us; speedup 1.0000x reference)
//
#include <hip/hip_runtime.h>

typedef __attribute__((ext_vector_type(8))) short short8;
typedef __attribute__((ext_vector_type(4))) float f32x4;

#define B_ 4
#define S_ 2048
#define H_ 16
#define DM 1024
#define DK 64

__device__ __forceinline__ unsigned short f2b(float f) {
  unsigned int u = __float_as_uint(f);
  u += 0x7fff + ((u >> 16) & 1);   // RNE
  return (unsigned short)(u >> 16);
}

// ---------------- fp32 -> bf16 conversion (z selects source array) --------
__global__ __launch_bounds__(256) void cvt_kernel(
    const float* __restrict__ a0, const float* __restrict__ a1,
    const float* __restrict__ a2, const float* __restrict__ a3,
    unsigned short* __restrict__ out, int n_per) {
  const float* src = (blockIdx.z == 0) ? a0 : (blockIdx.z == 1) ? a1
                   : (blockIdx.z == 2) ? a2 : a3;
  unsigned short* dst = out + (size_t)blockIdx.z * n_per;
  int i = (blockIdx.x * 256 + threadIdx.x) * 8;
  if (i >= n_per) return;
  float4 x0 = *(const float4*)&src[i];
  float4 x1 = *(const float4*)&src[i + 4];
  alignas(16) unsigned short r[8] = {f2b(x0.x), f2b(x0.y), f2b(x0.z), f2b(x0.w),
                                     f2b(x1.x), f2b(x1.y), f2b(x1.z), f2b(x1.w)};
  *(uint4*)&dst[i] = *(const uint4*)r;
}

// ---------------- mask (int32 0/1) -> bitmask ----------------------------
__global__ __launch_bounds__(256) void pack_kernel(const int* __restrict__ m,
                                                   unsigned int* __restrict__ out) {
  size_t i = (size_t)blockIdx.x * 256 + threadIdx.x;
  unsigned long long w = __ballot(m[i] != 0);
  if ((threadIdx.x & 31) == 0)
    out[i >> 5] = (unsigned int)(w >> (threadIdx.x & 32));
}

// ---------------- 128x128 bf16 GEMM core: C[m,n] = sum_k A[m,k]*W[n,k]+bias[n]
__device__ __forceinline__ void gemm128(
    const unsigned short* __restrict__ A, const unsigned short* __restrict__ W,
    const float* __restrict__ bias, int mode,
    unsigned short* __restrict__ outb, float* __restrict__ outf) {
  __shared__ unsigned short As[128 * 72];   // pad 64->72: <=2-way LDS aliasing
  __shared__ unsigned short Bs[128 * 72];
  const int m0 = blockIdx.x * 128;
  const int n0 = blockIdx.y * 128;
  const int t = threadIdx.x;
  const int lane = t & 63, wave = t >> 6;
  const int lr = lane & 15, quad = lane >> 4;
  const int wm = (wave >> 1) * 64, wn = (wave & 1) * 64;
  const int sr = t >> 3;         // staging row 0..31
  const int sc = (t & 7) * 8;    // staging col chunk

  const f32x4 zv = {0.f, 0.f, 0.f, 0.f};
  f32x4 acc[4][4];
#pragma unroll
  for (int mt = 0; mt < 4; mt++)
#pragma unroll
    for (int nt = 0; nt < 4; nt++) acc[mt][nt] = zv;

  for (int kb = 0; kb < DM; kb += 64) {
    __syncthreads();
#pragma unroll
    for (int i = 0; i < 4; i++) {
      int row = sr + i * 32;
      *(uint4*)&As[row * 72 + sc] = *(const uint4*)&A[(size_t)(m0 + row) * DM + kb + sc];
      *(uint4*)&Bs[row * 72 + sc] = *(const uint4*)&W[(size_t)(n0 + row) * DM + kb + sc];
    }
    __syncthreads();
#pragma unroll
    for (int ks = 0; ks < 2; ks++) {
      short8 af[4], bf[4];
#pragma unroll
      for (int mt = 0; mt < 4; mt++)
        af[mt] = *(const short8*)&As[(wm + mt * 16 + lr) * 72 + ks * 32 + quad * 8];
#pragma unroll
      for (int nt = 0; nt < 4; nt++)
        bf[nt] = *(const short8*)&Bs[(wn + nt * 16 + lr) * 72 + ks * 32 + quad * 8];
#pragma unroll
      for (int mt = 0; mt < 4; mt++)
#pragma unroll
        for (int nt = 0; nt < 4; nt++)
          acc[mt][nt] = __builtin_amdgcn_mfma_f32_16x16x32_bf16(af[mt], bf[nt], acc[mt][nt], 0, 0, 0);
    }
  }

  // epilogue: C row = quad*4+reg, col = lr  (m89-verified C/D layout)
#pragma unroll
  for (int mt = 0; mt < 4; mt++) {
#pragma unroll
    for (int nt = 0; nt < 4; nt++) {
#pragma unroll
      for (int reg = 0; reg < 4; reg++) {
        int gm = m0 + wm + mt * 16 + quad * 4 + reg;
        int gn = n0 + wn + nt * 16 + lr;
        float v = acc[mt][nt][reg] + bias[gn];
        if (mode == 0) {        // bf16 [B,H,S,DK]
          int b = gm >> 11, s = gm & (S_ - 1);
          int h = gn >> 6, dk = gn & 63;
          outb[(((size_t)(b * H_ + h) * S_ + s) << 6) + dk] = f2b(v);
        } else if (mode == 1) { // bf16 [B,H,DK,S]  (V transposed)
          int b = gm >> 11, s = gm & (S_ - 1);
          int h = gn >> 6, dk = gn & 63;
          outb[(size_t)((b * H_ + h) * 64 + dk) * S_ + s] = f2b(v);
        } else {                // fp32 [B*S, DM]
          outf[(size_t)gm * DM + gn] = v;
        }
      }
    }
  }
}

__global__ __launch_bounds__(256) void gemm_qkv_kernel(
    const unsigned short* __restrict__ xb, const unsigned short* __restrict__ wb,
    const float* __restrict__ bq, const float* __restrict__ bk, const float* __restrict__ bv,
    unsigned short* __restrict__ q_out, unsigned short* __restrict__ k_out,
    unsigned short* __restrict__ v_out) {
  int z = blockIdx.z;
  const unsigned short* A = xb + (size_t)z * (B_ * S_ * DM);
  const unsigned short* W = wb + (size_t)z * (DM * DM);
  const float* bias = (z == 0) ? bq : (z == 1) ? bk : bv;
  unsigned short* ob = (z == 0) ? q_out : (z == 1) ? k_out : v_out;
  gemm128(A, W, bias, (z == 2) ? 1 : 0, ob, nullptr);
}

__global__ __launch_bounds__(256) void gemm_out_kernel(
    const unsigned short* __restrict__ ab, const unsigned short* __restrict__ wb,
    const float* __restrict__ bo, float* __restrict__ out) {
  gemm128(ab, wb + (size_t)3 * (DM * DM), bo, 2, nullptr, out);
}

// ---------------- flash attention: 1 block = 128 q-rows of one (b,h) -----
__global__ __launch_bounds__(256) void attn_kernel(
    const unsigned short* __restrict__ qb, const unsigned short* __restrict__ kb,
    const unsigned short* __restrict__ vt, const unsigned int* __restrict__ mbits,
    unsigned short* __restrict__ ao) {
  __shared__ unsigned short Pl[4][2][16 * 72];  // per-wave P round-trip buffer
  const int bh = blockIdx.y;
  const int b = bh >> 4, h = bh & 15;
  const int t = threadIdx.x, lane = t & 63, wave = t >> 6;
  const int lr = lane & 15, quad = lane >> 4;
  const int q0 = blockIdx.x * 128 + wave * 32;  // wave owns 32 q-rows (2 m-tiles)
  const unsigned short* qp = qb + (size_t)bh * S_ * DK;
  const unsigned short* kp = kb + (size_t)bh * S_ * DK;
  const unsigned short* vp = vt + (size_t)bh * DK * S_;
  const unsigned int* mrow = mbits + (size_t)b * S_ * (S_ / 32);

  short8 qf[2][2];
#pragma unroll
  for (int mt = 0; mt < 2; mt++)
#pragma unroll
    for (int ks = 0; ks < 2; ks++)
      qf[mt][ks] = *(const short8*)&qp[(size_t)(q0 + mt * 16 + lr) * DK + ks * 32 + quad * 8];

  const f32x4 zv = {0.f, 0.f, 0.f, 0.f};
  f32x4 oacc[2][4];
  float ms[2][4], ls[2][4];
#pragma unroll
  for (int mt = 0; mt < 2; mt++)
#pragma unroll
    for (int r = 0; r < 4; r++) { ms[mt][r] = -1e30f; ls[mt][r] = 0.f; }
#pragma unroll
  for (int mt = 0; mt < 2; mt++)
#pragma unroll
    for (int nt = 0; nt < 4; nt++) oacc[mt][nt] = zv;

  for (int kt = 0; kt < S_ / 64; kt++) {
    const int kbase = kt * 64;
    // ---- S = Q K^T
    f32x4 sacc[2][4];
#pragma unroll
    for (int nt = 0; nt < 4; nt++) {
      short8 kf0 = *(const short8*)&kp[(size_t)(kbase + nt * 16 + lr) * DK + quad * 8];
      short8 kf1 = *(const short8*)&kp[(size_t)(kbase + nt * 16 + lr) * DK + 32 + quad * 8];
#pragma unroll
      for (int mt = 0; mt < 2; mt++) {
        f32x4 z = __builtin_amdgcn_mfma_f32_16x16x32_bf16(qf[mt][0], kf0, zv, 0, 0, 0);
        sacc[mt][nt] = __builtin_amdgcn_mfma_f32_16x16x32_bf16(qf[mt][1], kf1, z, 0, 0, 0);
      }
    }
    // ---- mask + online softmax (row = quad*4+r within each 16-row m-tile)
#pragma unroll
    for (int mt = 0; mt < 2; mt++) {
#pragma unroll
      for (int r = 0; r < 4; r++) {
        int row = q0 + mt * 16 + quad * 4 + r;
        uint2 mw = *(const uint2*)&mrow[(size_t)row * (S_ / 32) + kt * 2];
        float sv[4];
        float mx = -1e30f;
#pragma unroll
        for (int nt = 0; nt < 4; nt++) {
          unsigned int w = (nt < 2) ? mw.x : mw.y;
          float s = sacc[mt][nt][r] * 0.125f;
          bool keep = (w >> ((nt & 1) * 16 + lr)) & 1;
          s = keep ? s : -1e30f;
          sv[nt] = s;
          mx = fmaxf(mx, s);
        }
#pragma unroll
        for (int off = 1; off < 16; off <<= 1) mx = fmaxf(mx, __shfl_xor(mx, off, 64));
        float mold = ms[mt][r];
        float mnew = fmaxf(mold, mx);
        ms[mt][r] = mnew;
        float alpha = __expf(mold - mnew);       // fully-masked-so-far -> exp(0)=1
        float mu = fmaxf(mnew, -1e29f);          // masked: exp(-1e30-mu) underflows to 0
        float rs = 0.f;
#pragma unroll
        for (int nt = 0; nt < 4; nt++) {
          float e = __expf(sv[nt] - mu);
          rs += e;
          Pl[wave][mt][(quad * 4 + r) * 72 + nt * 16 + lr] = f2b(e);
        }
#pragma unroll
        for (int off = 1; off < 16; off <<= 1) rs += __shfl_xor(rs, off, 64);
        ls[mt][r] = ls[mt][r] * alpha + rs;
#pragma unroll
        for (int nt = 0; nt < 4; nt++) oacc[mt][nt][r] *= alpha;
      }
    }
    __syncthreads();  // P writes -> A-frag reads
    short8 pf[2][2];
#pragma unroll
    for (int mt = 0; mt < 2; mt++)
#pragma unroll
      for (int ks = 0; ks < 2; ks++)
        pf[mt][ks] = *(const short8*)&Pl[wave][mt][lr * 72 + ks * 32 + quad * 8];
    // ---- O += P V   (V^T layout: rows are d, k-contiguous in kpos)
#pragma unroll
    for (int nt = 0; nt < 4; nt++) {
      short8 vf0 = *(const short8*)&vp[(size_t)(nt * 16 + lr) * S_ + kbase + quad * 8];
      short8 vf1 = *(const short8*)&vp[(size_t)(nt * 16 + lr) * S_ + kbase + 32 + quad * 8];
#pragma unroll
      for (int mt = 0; mt < 2; mt++) {
        oacc[mt][nt] = __builtin_amdgcn_mfma_f32_16x16x32_bf16(pf[mt][0], vf0, oacc[mt][nt], 0, 0, 0);
        oacc[mt][nt] = __builtin_amdgcn_mfma_f32_16x16x32_bf16(pf[mt][1], vf1, oacc[mt][nt], 0, 0, 0);
      }
    }
    __syncthreads();  // protect Pl reuse next iteration
  }
  // ---- epilogue: O/l -> bf16 [B, S, H*DK]
#pragma unroll
  for (int mt = 0; mt < 2; mt++) {
#pragma unroll
    for (int r = 0; r < 4; r++) {
      float l = ls[mt][r];
      float inv = (l > 0.f) ? 1.f / l : 0.f;
      int row = q0 + mt * 16 + quad * 4 + r;
#pragma unroll
      for (int nt = 0; nt < 4; nt++)
        ao[((size_t)(b * S_ + row) * DM) + h * 64 + nt * 16 + lr] =
            f2b(oacc[mt][nt][r] * inv);
    }
  }
}

extern "C" void kernel_launch(void* const* d_in, const int* in_sizes, int n_in,
                              void* d_out, int out_size, void* d_ws, size_t ws_size,
                              hipStream_t stream) {
  const float* query = (const float*)d_in[0];
  const float* key   = (const float*)d_in[1];
  const float* value = (const float*)d_in[2];
  const int*   mask  = (const int*)d_in[3];
  const float* Wq = (const float*)d_in[4];
  const float* bq = (const float*)d_in[5];
  const float* Wk = (const float*)d_in[6];
  const float* bk = (const float*)d_in[7];
  const float* Wv = (const float*)d_in[8];
  const float* bv = (const float*)d_in[9];
  const float* Wo = (const float*)d_in[10];
  const float* bo = (const float*)d_in[11];
  float* out = (float*)d_out;
  char* ws = (char*)d_ws;

  // workspace layout (bytes)
  unsigned short* qb = (unsigned short*)(ws);                 // 16.78 MB [B,H,S,DK]
  unsigned short* kbf = (unsigned short*)(ws + 16777216);     // 16.78 MB [B,H,S,DK]
  unsigned short* vt = (unsigned short*)(ws + 33554432);      // 16.78 MB [B,H,DK,S]
  unsigned short* wb = (unsigned short*)(ws + 50331648);      // 8.39 MB  4x[DM,DM]
  unsigned int*   mb = (unsigned int*)(ws + 58720256);        // 2.10 MB  bits
  unsigned short* xb = (unsigned short*)(ws + 60817408);      // 50.33 MB bf16 q,k,v inputs
  unsigned short* ao = (unsigned short*)(ws + 60817408);      // alias: reused after QKV GEMM

  cvt_kernel<<<dim3(4096, 1, 3), 256, 0, stream>>>(query, key, value, nullptr, xb, B_ * S_ * DM);
  cvt_kernel<<<dim3(512, 1, 4), 256, 0, stream>>>(Wq, Wk, Wv, Wo, wb, DM * DM);
  pack_kernel<<<dim3(65536), 256, 0, stream>>>(mask, mb);
  gemm_qkv_kernel<<<dim3(64, 8, 3), 256, 0, stream>>>(xb, wb, bq, bk, bv, qb, kbf, vt);
  attn_kernel<<<dim3(16, 64), 256, 0, stream>>>(qb, kbf, vt, mb, ao);
  gemm_out_kernel<<<dim3(64, 8), 256, 0, stream>>>(ao, wb, bo, out);
}

// Round 2
// 680.057 us; speedup vs baseline: 1.1830x; 1.1830x over previous
//
#include <hip/hip_runtime.h>

typedef __attribute__((ext_vector_type(8))) short short8;
typedef __attribute__((ext_vector_type(4))) float f32x4;

#define B_ 4
#define S_ 2048
#define H_ 16
#define DM 1024
#define DK 64

// 0.125 * log2(e): folds the 1/sqrt(64) score scale + exp->exp2 conversion into Q
#define QSCALE 0.18033688011112042f

__device__ __forceinline__ unsigned short f2b(float f) {
  unsigned int u = __float_as_uint(f);
  u += 0x7fff + ((u >> 16) & 1);   // RNE
  return (unsigned short)(u >> 16);
}

__device__ __forceinline__ void gload_lds16(const void* g, void* l) {
  __builtin_amdgcn_global_load_lds(
      (const __attribute__((address_space(1))) unsigned int*)g,
      (__attribute__((address_space(3))) unsigned int*)l, 16, 0, 0);
}

// ---------------- fp32 -> bf16 conversion (z selects source array) --------
__global__ __launch_bounds__(256) void cvt_kernel(
    const float* __restrict__ a0, const float* __restrict__ a1,
    const float* __restrict__ a2, const float* __restrict__ a3,
    unsigned short* __restrict__ out, int n_per) {
  const float* src = (blockIdx.z == 0) ? a0 : (blockIdx.z == 1) ? a1
                   : (blockIdx.z == 2) ? a2 : a3;
  unsigned short* dst = out + (size_t)blockIdx.z * n_per;
  int i = (blockIdx.x * 256 + threadIdx.x) * 8;
  if (i >= n_per) return;
  float4 x0 = *(const float4*)&src[i];
  float4 x1 = *(const float4*)&src[i + 4];
  alignas(16) unsigned short r[8] = {f2b(x0.x), f2b(x0.y), f2b(x0.z), f2b(x0.w),
                                     f2b(x1.x), f2b(x1.y), f2b(x1.z), f2b(x1.w)};
  *(uint4*)&dst[i] = *(const uint4*)r;
}

// ---------------- mask (int32 0/1) -> bitmask ----------------------------
__global__ __launch_bounds__(256) void pack_kernel(const int* __restrict__ m,
                                                   unsigned int* __restrict__ out) {
  size_t i = (size_t)blockIdx.x * 256 + threadIdx.x;
  unsigned long long w = __ballot(m[i] != 0);
  if ((threadIdx.x & 31) == 0)
    out[i >> 5] = (unsigned int)(w >> (threadIdx.x & 32));
}

// ---------- 128x128 bf16 GEMM, m97 structure: global_load_lds staging -----
// C[m,n] = (sum_k A[m,k]*W[n,k] + bias[n]) * scale
__device__ __forceinline__ void gemm128(
    const unsigned short* __restrict__ A, const unsigned short* __restrict__ W,
    const float* __restrict__ bias, float scale, int mode,
    unsigned short* __restrict__ outb, float* __restrict__ outf) {
  __shared__ unsigned short As[128 * 64];   // unpadded: global_load_lds dest
  __shared__ unsigned short Bs[128 * 64];
  const int m0 = blockIdx.x * 128;
  const int n0 = blockIdx.y * 128;
  const int t = threadIdx.x;
  const int lane = t & 63, wave = t >> 6;
  const int lr = lane & 15, quad = lane >> 4;
  const int wm = (wave >> 1) * 64, wn = (wave & 1) * 64;
  const int srow = (lane >> 3);        // within-chunk row 0..7
  const int scol = (lane & 7) * 8;     // within-row col chunk

  const f32x4 zv = {0.f, 0.f, 0.f, 0.f};
  f32x4 acc[4][4];
#pragma unroll
  for (int mt = 0; mt < 4; mt++)
#pragma unroll
    for (int nt = 0; nt < 4; nt++) acc[mt][nt] = zv;

  for (int kb = 0; kb < DM; kb += 64) {
    __syncthreads();
#pragma unroll
    for (int i = 0; i < 4; i++) {
      int c = wave * 4 + i;            // chunk of 8 rows (1 KB)
      int row = c * 8 + srow;
      gload_lds16(&A[(size_t)(m0 + row) * DM + kb + scol], &As[c * 512]);
      gload_lds16(&W[(size_t)(n0 + row) * DM + kb + scol], &Bs[c * 512]);
    }
    __syncthreads();
#pragma unroll
    for (int ks = 0; ks < 2; ks++) {
      short8 af[4], bf[4];
#pragma unroll
      for (int mt = 0; mt < 4; mt++)
        af[mt] = *(const short8*)&As[(wm + mt * 16 + lr) * 64 + ks * 32 + quad * 8];
#pragma unroll
      for (int nt = 0; nt < 4; nt++)
        bf[nt] = *(const short8*)&Bs[(wn + nt * 16 + lr) * 64 + ks * 32 + quad * 8];
#pragma unroll
      for (int mt = 0; mt < 4; mt++)
#pragma unroll
        for (int nt = 0; nt < 4; nt++)
          acc[mt][nt] = __builtin_amdgcn_mfma_f32_16x16x32_bf16(af[mt], bf[nt], acc[mt][nt], 0, 0, 0);
    }
  }

  // epilogue: C row = quad*4+reg, col = lr  (m89-verified C/D layout)
#pragma unroll
  for (int mt = 0; mt < 4; mt++) {
#pragma unroll
    for (int nt = 0; nt < 4; nt++) {
#pragma unroll
      for (int reg = 0; reg < 4; reg++) {
        int gm = m0 + wm + mt * 16 + quad * 4 + reg;
        int gn = n0 + wn + nt * 16 + lr;
        float v = (acc[mt][nt][reg] + bias[gn]) * scale;
        if (mode == 0) {        // bf16 [B,H,S,DK]
          int b = gm >> 11, s = gm & (S_ - 1);
          int h = gn >> 6, dk = gn & 63;
          outb[(((size_t)(b * H_ + h) * S_ + s) << 6) + dk] = f2b(v);
        } else if (mode == 1) { // bf16 [B,H,DK,S]  (V transposed)
          int b = gm >> 11, s = gm & (S_ - 1);
          int h = gn >> 6, dk = gn & 63;
          outb[(size_t)((b * H_ + h) * 64 + dk) * S_ + s] = f2b(v);
        } else {                // fp32 [B*S, DM]
          outf[(size_t)gm * DM + gn] = v;
        }
      }
    }
  }
}

__global__ __launch_bounds__(256) void gemm_qkv_kernel(
    const unsigned short* __restrict__ xb, const unsigned short* __restrict__ wb,
    const float* __restrict__ bq, const float* __restrict__ bk, const float* __restrict__ bv,
    unsigned short* __restrict__ q_out, unsigned short* __restrict__ k_out,
    unsigned short* __restrict__ v_out) {
  int z = blockIdx.z;
  const unsigned short* A = xb + (size_t)z * (B_ * S_ * DM);
  const unsigned short* W = wb + (size_t)z * (DM * DM);
  const float* bias = (z == 0) ? bq : (z == 1) ? bk : bv;
  unsigned short* ob = (z == 0) ? q_out : (z == 1) ? k_out : v_out;
  gemm128(A, W, bias, (z == 0) ? QSCALE : 1.0f, (z == 2) ? 1 : 0, ob, nullptr);
}

__global__ __launch_bounds__(256) void gemm_out_kernel(
    const unsigned short* __restrict__ ab, const unsigned short* __restrict__ wb,
    const float* __restrict__ bo, float* __restrict__ out) {
  gemm128(ab, wb + (size_t)3 * (DM * DM), bo, 1.0f, 2, nullptr, out);
}

// ---------------- flash attention v2: no max, no shfl, no barriers -------
// Q pre-scaled by 0.125*log2(e); p = exp2(s) * maskbit; l = P @ ones (MFMA)
__global__ __launch_bounds__(256) void attn_kernel(
    const unsigned short* __restrict__ qb, const unsigned short* __restrict__ kb,
    const unsigned short* __restrict__ vt, const unsigned int* __restrict__ mbits,
    unsigned short* __restrict__ ao) {
  __shared__ unsigned short Pl[4][32 * 72];  // per-wave P buffer (C->A layout hop)
  const int bh = blockIdx.y;
  const int b = bh >> 4, h = bh & 15;
  const int t = threadIdx.x, lane = t & 63, wave = t >> 6;
  const int lr = lane & 15, quad = lane >> 4;
  const int q0 = blockIdx.x * 128 + wave * 32;  // wave owns 32 q-rows
  const unsigned short* qp = qb + (size_t)bh * S_ * DK;
  const unsigned short* kp = kb + (size_t)bh * S_ * DK;
  const unsigned short* vp = vt + (size_t)bh * DK * S_;
  const unsigned int* mrow = mbits + (size_t)b * S_ * (S_ / 32);
  unsigned short* plw = &Pl[wave][0];

  short8 qf[2][2];
#pragma unroll
  for (int mt = 0; mt < 2; mt++)
#pragma unroll
    for (int ks = 0; ks < 2; ks++)
      qf[mt][ks] = *(const short8*)&qp[(size_t)(q0 + mt * 16 + lr) * DK + ks * 32 + quad * 8];

  const f32x4 zv = {0.f, 0.f, 0.f, 0.f};
  short8 ones;
#pragma unroll
  for (int i = 0; i < 8; i++) ones[i] = (short)0x3F80;  // bf16 1.0
  f32x4 oacc[2][4], lacc[2];
#pragma unroll
  for (int mt = 0; mt < 2; mt++) {
    lacc[mt] = zv;
#pragma unroll
    for (int nt = 0; nt < 4; nt++) oacc[mt][nt] = zv;
  }

  for (int kt = 0; kt < S_ / 64; kt++) {
    const int kbase = kt * 64;
    // ---- S = Q K^T (exp2 domain; scale already folded into Q)
    f32x4 sacc[2][4];
#pragma unroll
    for (int nt = 0; nt < 4; nt++) {
      short8 kf0 = *(const short8*)&kp[(size_t)(kbase + nt * 16 + lr) * DK + quad * 8];
      short8 kf1 = *(const short8*)&kp[(size_t)(kbase + nt * 16 + lr) * DK + 32 + quad * 8];
#pragma unroll
      for (int mt = 0; mt < 2; mt++) {
        f32x4 z = __builtin_amdgcn_mfma_f32_16x16x32_bf16(qf[mt][0], kf0, zv, 0, 0, 0);
        sacc[mt][nt] = __builtin_amdgcn_mfma_f32_16x16x32_bf16(qf[mt][1], kf1, z, 0, 0, 0);
      }
    }
    // ---- p = exp2(s) * maskbit; write P to per-wave LDS (C-layout rows)
#pragma unroll
    for (int mt = 0; mt < 2; mt++) {
#pragma unroll
      for (int r = 0; r < 4; r++) {
        int row = q0 + mt * 16 + quad * 4 + r;
        uint2 mw = *(const uint2*)&mrow[(size_t)row * (S_ / 32) + kt * 2];
#pragma unroll
        for (int nt = 0; nt < 4; nt++) {
          unsigned int w = (nt < 2) ? mw.x : mw.y;
          float e = exp2f(sacc[mt][nt][r]);
          unsigned int bit = (w >> ((nt & 1) * 16 + lr)) & 1u;
          e *= (float)bit;
          plw[(mt * 16 + quad * 4 + r) * 72 + nt * 16 + lr] = f2b(e);
        }
      }
    }
    // wave-local LDS RAW: hardware in-order DS + compiler lgkmcnt, no barrier
    short8 pf[2][2];
#pragma unroll
    for (int mt = 0; mt < 2; mt++)
#pragma unroll
      for (int ks = 0; ks < 2; ks++)
        pf[mt][ks] = *(const short8*)&plw[(mt * 16 + lr) * 72 + ks * 32 + quad * 8];
    // ---- l += P @ 1  (C-layout: every lane gets its rows' sums in regs)
#pragma unroll
    for (int mt = 0; mt < 2; mt++) {
      lacc[mt] = __builtin_amdgcn_mfma_f32_16x16x32_bf16(pf[mt][0], ones, lacc[mt], 0, 0, 0);
      lacc[mt] = __builtin_amdgcn_mfma_f32_16x16x32_bf16(pf[mt][1], ones, lacc[mt], 0, 0, 0);
    }
    // ---- O += P V   (V^T layout: rows are d, k-contiguous in kpos)
#pragma unroll
    for (int nt = 0; nt < 4; nt++) {
      short8 vf0 = *(const short8*)&vp[(size_t)(nt * 16 + lr) * S_ + kbase + quad * 8];
      short8 vf1 = *(const short8*)&vp[(size_t)(nt * 16 + lr) * S_ + kbase + 32 + quad * 8];
#pragma unroll
      for (int mt = 0; mt < 2; mt++) {
        oacc[mt][nt] = __builtin_amdgcn_mfma_f32_16x16x32_bf16(pf[mt][0], vf0, oacc[mt][nt], 0, 0, 0);
        oacc[mt][nt] = __builtin_amdgcn_mfma_f32_16x16x32_bf16(pf[mt][1], vf1, oacc[mt][nt], 0, 0, 0);
      }
    }
  }
  // ---- epilogue: O/l -> bf16 [B, S, H*DK]; fully-masked row -> 0
#pragma unroll
  for (int mt = 0; mt < 2; mt++) {
#pragma unroll
    for (int r = 0; r < 4; r++) {
      float l = lacc[mt][r];
      float inv = (l > 0.f) ? 1.f / l : 0.f;
      int row = q0 + mt * 16 + quad * 4 + r;
#pragma unroll
      for (int nt = 0; nt < 4; nt++)
        ao[((size_t)(b * S_ + row) * DM) + h * 64 + nt * 16 + lr] =
            f2b(oacc[mt][nt][r] * inv);
    }
  }
}

extern "C" void kernel_launch(void* const* d_in, const int* in_sizes, int n_in,
                              void* d_out, int out_size, void* d_ws, size_t ws_size,
                              hipStream_t stream) {
  const float* query = (const float*)d_in[0];
  const float* key   = (const float*)d_in[1];
  const float* value = (const float*)d_in[2];
  const int*   mask  = (const int*)d_in[3];
  const float* Wq = (const float*)d_in[4];
  const float* bq = (const float*)d_in[5];
  const float* Wk = (const float*)d_in[6];
  const float* bk = (const float*)d_in[7];
  const float* Wv = (const float*)d_in[8];
  const float* bv = (const float*)d_in[9];
  const float* Wo = (const float*)d_in[10];
  const float* bo = (const float*)d_in[11];
  float* out = (float*)d_out;
  char* ws = (char*)d_ws;

  // workspace layout (bytes)
  unsigned short* qb = (unsigned short*)(ws);                 // 16.78 MB [B,H,S,DK] (pre-scaled)
  unsigned short* kbf = (unsigned short*)(ws + 16777216);     // 16.78 MB [B,H,S,DK]
  unsigned short* vt = (unsigned short*)(ws + 33554432);      // 16.78 MB [B,H,DK,S]
  unsigned short* wb = (unsigned short*)(ws + 50331648);      // 8.39 MB  4x[DM,DM]
  unsigned int*   mb = (unsigned int*)(ws + 58720256);        // 2.10 MB  bits
  unsigned short* xb = (unsigned short*)(ws + 60817408);      // 50.33 MB bf16 q,k,v inputs
  unsigned short* ao = (unsigned short*)(ws + 60817408);      // alias: reused after QKV GEMM

  cvt_kernel<<<dim3(4096, 1, 3), 256, 0, stream>>>(query, key, value, nullptr, xb, B_ * S_ * DM);
  cvt_kernel<<<dim3(512, 1, 4), 256, 0, stream>>>(Wq, Wk, Wv, Wo, wb, DM * DM);
  pack_kernel<<<dim3(65536), 256, 0, stream>>>(mask, mb);
  gemm_qkv_kernel<<<dim3(64, 8, 3), 256, 0, stream>>>(xb, wb, bq, bk, bv, qb, kbf, vt);
  attn_kernel<<<dim3(16, 64), 256, 0, stream>>>(qb, kbf, vt, mb, ao);
  gemm_out_kernel<<<dim3(64, 8), 256, 0, stream>>>(ao, wb, bo, out);
}

// Round 3
// 496.742 us; speedup vs baseline: 1.6196x; 1.3690x over previous
//
#include <hip/hip_runtime.h>

typedef __attribute__((ext_vector_type(8))) short short8;
typedef __attribute__((ext_vector_type(4))) float f32x4;

#define B_ 4
#define S_ 2048
#define H_ 16
#define DM 1024
#define DK 64

// 0.125 * log2(e): folds the 1/sqrt(64) score scale + exp->exp2 conversion into Q
#define QSCALE 0.18033688011112042f

__device__ __forceinline__ unsigned short f2b(float f) {
  unsigned int u = __float_as_uint(f);
  u += 0x7fff + ((u >> 16) & 1);   // RNE
  return (unsigned short)(u >> 16);
}

__device__ __forceinline__ void gload_lds16(const void* g, void* l) {
  __builtin_amdgcn_global_load_lds(
      (const __attribute__((address_space(1))) unsigned int*)g,
      (__attribute__((address_space(3))) unsigned int*)l, 16, 0, 0);
}

// ---------------- fp32 -> bf16 conversion (z selects source array) --------
__global__ __launch_bounds__(256) void cvt_kernel(
    const float* __restrict__ a0, const float* __restrict__ a1,
    const float* __restrict__ a2, const float* __restrict__ a3,
    unsigned short* __restrict__ out, int n_per) {
  const float* src = (blockIdx.z == 0) ? a0 : (blockIdx.z == 1) ? a1
                   : (blockIdx.z == 2) ? a2 : a3;
  unsigned short* dst = out + (size_t)blockIdx.z * n_per;
  int i = (blockIdx.x * 256 + threadIdx.x) * 8;
  if (i >= n_per) return;
  float4 x0 = *(const float4*)&src[i];
  float4 x1 = *(const float4*)&src[i + 4];
  alignas(16) unsigned short r[8] = {f2b(x0.x), f2b(x0.y), f2b(x0.z), f2b(x0.w),
                                     f2b(x1.x), f2b(x1.y), f2b(x1.z), f2b(x1.w)};
  *(uint4*)&dst[i] = *(const uint4*)r;
}

// ---------------- mask (int32 0/1) -> bitmask ----------------------------
__global__ __launch_bounds__(256) void pack_kernel(const int* __restrict__ m,
                                                   unsigned int* __restrict__ out) {
  size_t i = (size_t)blockIdx.x * 256 + threadIdx.x;
  unsigned long long w = __ballot(m[i] != 0);
  if ((threadIdx.x & 31) == 0)
    out[i >> 5] = (unsigned int)(w >> (threadIdx.x & 32));
}

// ---------- 128x128 bf16 GEMM, m97 structure: global_load_lds staging -----
// C[m,n] = (sum_k A[m,k]*W[n,k] + bias[n]) * scale
__device__ __forceinline__ void gemm128(
    const unsigned short* __restrict__ A, const unsigned short* __restrict__ W,
    const float* __restrict__ bias, float scale, int mode,
    unsigned short* __restrict__ outb, float* __restrict__ outf) {
  __shared__ unsigned short As[128 * 64];   // unpadded: global_load_lds dest
  __shared__ unsigned short Bs[128 * 64];
  const int m0 = blockIdx.x * 128;
  const int n0 = blockIdx.y * 128;
  const int t = threadIdx.x;
  const int lane = t & 63, wave = t >> 6;
  const int lr = lane & 15, quad = lane >> 4;
  const int wm = (wave >> 1) * 64, wn = (wave & 1) * 64;
  const int srow = (lane >> 3);        // within-chunk row 0..7
  const int scol = (lane & 7) * 8;     // within-row col chunk

  const f32x4 zv = {0.f, 0.f, 0.f, 0.f};
  f32x4 acc[4][4];
#pragma unroll
  for (int mt = 0; mt < 4; mt++)
#pragma unroll
    for (int nt = 0; nt < 4; nt++) acc[mt][nt] = zv;

  for (int kb = 0; kb < DM; kb += 64) {
    __syncthreads();
#pragma unroll
    for (int i = 0; i < 4; i++) {
      int c = wave * 4 + i;            // chunk of 8 rows (1 KB)
      int row = c * 8 + srow;
      gload_lds16(&A[(size_t)(m0 + row) * DM + kb + scol], &As[c * 512]);
      gload_lds16(&W[(size_t)(n0 + row) * DM + kb + scol], &Bs[c * 512]);
    }
    __syncthreads();
#pragma unroll
    for (int ks = 0; ks < 2; ks++) {
      short8 af[4], bf[4];
#pragma unroll
      for (int mt = 0; mt < 4; mt++)
        af[mt] = *(const short8*)&As[(wm + mt * 16 + lr) * 64 + ks * 32 + quad * 8];
#pragma unroll
      for (int nt = 0; nt < 4; nt++)
        bf[nt] = *(const short8*)&Bs[(wn + nt * 16 + lr) * 64 + ks * 32 + quad * 8];
#pragma unroll
      for (int mt = 0; mt < 4; mt++)
#pragma unroll
        for (int nt = 0; nt < 4; nt++)
          acc[mt][nt] = __builtin_amdgcn_mfma_f32_16x16x32_bf16(af[mt], bf[nt], acc[mt][nt], 0, 0, 0);
    }
  }

  // epilogue: C row = quad*4+reg, col = lr  (m89-verified C/D layout)
#pragma unroll
  for (int mt = 0; mt < 4; mt++) {
#pragma unroll
    for (int nt = 0; nt < 4; nt++) {
#pragma unroll
      for (int reg = 0; reg < 4; reg++) {
        int gm = m0 + wm + mt * 16 + quad * 4 + reg;
        int gn = n0 + wn + nt * 16 + lr;
        float v = (acc[mt][nt][reg] + bias[gn]) * scale;
        if (mode == 0) {        // bf16 [B,H,S,DK]
          int b = gm >> 11, s = gm & (S_ - 1);
          int h = gn >> 6, dk = gn & 63;
          outb[(((size_t)(b * H_ + h) * S_ + s) << 6) + dk] = f2b(v);
        } else if (mode == 1) { // bf16 [B,H,DK,S]  (V transposed)
          int b = gm >> 11, s = gm & (S_ - 1);
          int h = gn >> 6, dk = gn & 63;
          outb[(size_t)((b * H_ + h) * 64 + dk) * S_ + s] = f2b(v);
        } else {                // fp32 [B*S, DM]
          outf[(size_t)gm * DM + gn] = v;
        }
      }
    }
  }
}

__global__ __launch_bounds__(256) void gemm_qkv_kernel(
    const unsigned short* __restrict__ xb, const unsigned short* __restrict__ wb,
    const float* __restrict__ bq, const float* __restrict__ bk, const float* __restrict__ bv,
    unsigned short* __restrict__ q_out, unsigned short* __restrict__ k_out,
    unsigned short* __restrict__ v_out) {
  int z = blockIdx.z;
  const unsigned short* A = xb + (size_t)z * (B_ * S_ * DM);
  const unsigned short* W = wb + (size_t)z * (DM * DM);
  const float* bias = (z == 0) ? bq : (z == 1) ? bk : bv;
  unsigned short* ob = (z == 0) ? q_out : (z == 1) ? k_out : v_out;
  gemm128(A, W, bias, (z == 0) ? QSCALE : 1.0f, (z == 2) ? 1 : 0, ob, nullptr);
}

__global__ __launch_bounds__(256) void gemm_out_kernel(
    const unsigned short* __restrict__ ab, const unsigned short* __restrict__ wb,
    const float* __restrict__ bo, float* __restrict__ out) {
  gemm128(ab, wb + (size_t)3 * (DM * DM), bo, 1.0f, 2, nullptr, out);
}

// ------- flash attention v3: cooperative LDS staging (m97 structure) ------
// K-tile (64x64) and V^T-tile (64x64) staged via global_load_lds with
// odd-row 64B-half XOR swizzle (bank-spread); per-wave P round-trip in LDS.
__global__ __launch_bounds__(256, 4) void attn_kernel(
    const unsigned short* __restrict__ qb, const unsigned short* __restrict__ kb,
    const unsigned short* __restrict__ vt, const unsigned int* __restrict__ mbits,
    unsigned short* __restrict__ ao) {
  __shared__ unsigned short Ks[64 * 64];     // rows: key, 16B chunk c at c^((row&1)<<2)
  __shared__ unsigned short Vs[64 * 64];     // rows: d,   same swizzle
  __shared__ unsigned short Pl[4][32 * 72];  // per-wave P buffer (C->A layout hop)
  const int bh = blockIdx.y;
  const int b = bh >> 4, h = bh & 15;
  const int t = threadIdx.x, lane = t & 63, wave = t >> 6;
  const int lr = lane & 15, quad = lane >> 4;
  const int q0 = blockIdx.x * 128 + wave * 32;  // wave owns 32 q-rows
  const unsigned short* qp = qb + (size_t)bh * S_ * DK;
  const unsigned short* kp = kb + (size_t)bh * S_ * DK;
  const unsigned short* vp = vt + (size_t)bh * DK * S_;
  const unsigned int* mrow = mbits + (size_t)b * S_ * (S_ / 32);
  unsigned short* plw = &Pl[wave][0];

  // staging decomposition: thread -> (row 0..31, 16B chunk 0..7), swizzled chunk
  const int trow = t >> 3;
  const int tsw = (t & 7) ^ ((trow & 1) << 2);
  const int wbase = wave * 512;              // shorts; lane*16B appended by HW
  // read-side swizzled chunk offsets (shorts), invariant per lane
  const int sx4 = (lr & 1) << 2;
  const int c0 = (quad ^ sx4) * 8;           // ks=0 chunk
  const int c1 = ((4 + quad) ^ sx4) * 8;     // ks=1 chunk
  const unsigned int sh0 = 31 - lr, sh1 = 15 - lr;  // mask bit -> sign extract

  short8 qf[2][2];
#pragma unroll
  for (int mt = 0; mt < 2; mt++)
#pragma unroll
    for (int ks = 0; ks < 2; ks++)
      qf[mt][ks] = *(const short8*)&qp[(size_t)(q0 + mt * 16 + lr) * DK + ks * 32 + quad * 8];

  const f32x4 zv = {0.f, 0.f, 0.f, 0.f};
  short8 ones;
#pragma unroll
  for (int i = 0; i < 8; i++) ones[i] = (short)0x3F80;  // bf16 1.0
  f32x4 oacc[2][4], lacc[2];
#pragma unroll
  for (int mt = 0; mt < 2; mt++) {
    lacc[mt] = zv;
#pragma unroll
    for (int nt = 0; nt < 4; nt++) oacc[mt][nt] = zv;
  }

  for (int kt = 0; kt < S_ / 64; kt++) {
    const int kbase = kt * 64;
    // mask prefetch (latency overlaps the staging barrier + vmcnt drain)
    uint2 mw[2][4];
#pragma unroll
    for (int mt = 0; mt < 2; mt++)
#pragma unroll
      for (int r = 0; r < 4; r++)
        mw[mt][r] = *(const uint2*)&mrow[(size_t)(q0 + mt * 16 + quad * 4 + r) * (S_ / 32) + kt * 2];

    __syncthreads();  // all waves done reading previous Ks/Vs
    gload_lds16(kp + (size_t)(kbase + trow) * DK + tsw * 8,      &Ks[wbase]);
    gload_lds16(kp + (size_t)(kbase + 32 + trow) * DK + tsw * 8, &Ks[2048 + wbase]);
    gload_lds16(vp + (size_t)trow * S_ + kbase + tsw * 8,        &Vs[wbase]);
    gload_lds16(vp + (size_t)(32 + trow) * S_ + kbase + tsw * 8, &Vs[2048 + wbase]);
    __syncthreads();  // staging visible

    // ---- S = Q K^T (exp2 domain; scale folded into Q)
    f32x4 sacc[2][4];
#pragma unroll
    for (int nt = 0; nt < 4; nt++) {
      short8 kf0 = *(const short8*)&Ks[(nt * 16 + lr) * 64 + c0];
      short8 kf1 = *(const short8*)&Ks[(nt * 16 + lr) * 64 + c1];
#pragma unroll
      for (int mt = 0; mt < 2; mt++) {
        f32x4 z = __builtin_amdgcn_mfma_f32_16x16x32_bf16(qf[mt][0], kf0, zv, 0, 0, 0);
        sacc[mt][nt] = __builtin_amdgcn_mfma_f32_16x16x32_bf16(qf[mt][1], kf1, z, 0, 0, 0);
      }
    }
    // ---- p = exp2(s) & maskbit -> per-wave LDS (C-layout rows)
#pragma unroll
    for (int mt = 0; mt < 2; mt++) {
#pragma unroll
      for (int r = 0; r < 4; r++) {
        uint2 m2 = mw[mt][r];
#pragma unroll
        for (int nt = 0; nt < 4; nt++) {
          unsigned int w = (nt < 2) ? m2.x : m2.y;
          unsigned int shl = (nt & 1) ? sh1 : sh0;
          float e = exp2f(sacc[mt][nt][r]);
          unsigned int pb = (__float_as_uint(e) + 0x8000u) >> 16;  // round-half-up bf16
          pb &= (unsigned int)(((int)(w << shl)) >> 31);           // 0 or all-ones
          plw[(mt * 16 + quad * 4 + r) * 72 + nt * 16 + lr] = (unsigned short)pb;
        }
      }
    }
    // wave-local LDS RAW: compiler lgkmcnt, no barrier needed
    short8 pf[2][2];
#pragma unroll
    for (int mt = 0; mt < 2; mt++)
#pragma unroll
      for (int ks = 0; ks < 2; ks++)
        pf[mt][ks] = *(const short8*)&plw[(mt * 16 + lr) * 72 + ks * 32 + quad * 8];
    // ---- l += P @ 1
#pragma unroll
    for (int mt = 0; mt < 2; mt++) {
      lacc[mt] = __builtin_amdgcn_mfma_f32_16x16x32_bf16(pf[mt][0], ones, lacc[mt], 0, 0, 0);
      lacc[mt] = __builtin_amdgcn_mfma_f32_16x16x32_bf16(pf[mt][1], ones, lacc[mt], 0, 0, 0);
    }
    // ---- O += P V   (Vs rows are d, cols key-in-tile, swizzled)
#pragma unroll
    for (int nt = 0; nt < 4; nt++) {
      short8 vf0 = *(const short8*)&Vs[(nt * 16 + lr) * 64 + c0];
      short8 vf1 = *(const short8*)&Vs[(nt * 16 + lr) * 64 + c1];
#pragma unroll
      for (int mt = 0; mt < 2; mt++) {
        oacc[mt][nt] = __builtin_amdgcn_mfma_f32_16x16x32_bf16(pf[mt][0], vf0, oacc[mt][nt], 0, 0, 0);
        oacc[mt][nt] = __builtin_amdgcn_mfma_f32_16x16x32_bf16(pf[mt][1], vf1, oacc[mt][nt], 0, 0, 0);
      }
    }
  }
  // ---- epilogue: O/l -> bf16 [B, S, H*DK]; fully-masked row -> 0
#pragma unroll
  for (int mt = 0; mt < 2; mt++) {
#pragma unroll
    for (int r = 0; r < 4; r++) {
      float l = lacc[mt][r];
      float inv = (l > 0.f) ? 1.f / l : 0.f;
      int row = q0 + mt * 16 + quad * 4 + r;
#pragma unroll
      for (int nt = 0; nt < 4; nt++)
        ao[((size_t)(b * S_ + row) * DM) + h * 64 + nt * 16 + lr] =
            f2b(oacc[mt][nt][r] * inv);
    }
  }
}

extern "C" void kernel_launch(void* const* d_in, const int* in_sizes, int n_in,
                              void* d_out, int out_size, void* d_ws, size_t ws_size,
                              hipStream_t stream) {
  const float* query = (const float*)d_in[0];
  const float* key   = (const float*)d_in[1];
  const float* value = (const float*)d_in[2];
  const int*   mask  = (const int*)d_in[3];
  const float* Wq = (const float*)d_in[4];
  const float* bq = (const float*)d_in[5];
  const float* Wk = (const float*)d_in[6];
  const float* bk = (const float*)d_in[7];
  const float* Wv = (const float*)d_in[8];
  const float* bv = (const float*)d_in[9];
  const float* Wo = (const float*)d_in[10];
  const float* bo = (const float*)d_in[11];
  float* out = (float*)d_out;
  char* ws = (char*)d_ws;

  // workspace layout (bytes)
  unsigned short* qb = (unsigned short*)(ws);                 // 16.78 MB [B,H,S,DK] (pre-scaled)
  unsigned short* kbf = (unsigned short*)(ws + 16777216);     // 16.78 MB [B,H,S,DK]
  unsigned short* vt = (unsigned short*)(ws + 33554432);      // 16.78 MB [B,H,DK,S]
  unsigned short* wb = (unsigned short*)(ws + 50331648);      // 8.39 MB  4x[DM,DM]
  unsigned int*   mb = (unsigned int*)(ws + 58720256);        // 2.10 MB  bits
  unsigned short* xb = (unsigned short*)(ws + 60817408);      // 50.33 MB bf16 q,k,v inputs
  unsigned short* ao = (unsigned short*)(ws + 60817408);      // alias: reused after QKV GEMM

  cvt_kernel<<<dim3(4096, 1, 3), 256, 0, stream>>>(query, key, value, nullptr, xb, B_ * S_ * DM);
  cvt_kernel<<<dim3(512, 1, 4), 256, 0, stream>>>(Wq, Wk, Wv, Wo, wb, DM * DM);
  pack_kernel<<<dim3(65536), 256, 0, stream>>>(mask, mb);
  gemm_qkv_kernel<<<dim3(64, 8, 3), 256, 0, stream>>>(xb, wb, bq, bk, bv, qb, kbf, vt);
  attn_kernel<<<dim3(16, 64), 256, 0, stream>>>(qb, kbf, vt, mb, ao);
  gemm_out_kernel<<<dim3(64, 8), 256, 0, stream>>>(ao, wb, bo, out);
}

// Round 4
// 472.375 us; speedup vs baseline: 1.7031x; 1.0516x over previous
//
#include <hip/hip_runtime.h>

typedef __attribute__((ext_vector_type(8))) short short8;
typedef __attribute__((ext_vector_type(4))) float f32x4;

#define B_ 4
#define S_ 2048
#define H_ 16
#define DM 1024
#define DK 64

// 0.125 * log2(e): folds the 1/sqrt(64) score scale + exp->exp2 conversion into Q
#define QSCALE 0.18033688011112042f

__device__ __forceinline__ unsigned short f2b(float f) {
  unsigned int u = __float_as_uint(f);
  u += 0x7fff + ((u >> 16) & 1);   // RNE
  return (unsigned short)(u >> 16);
}

__device__ __forceinline__ void gload_lds16(const void* g, void* l) {
  __builtin_amdgcn_global_load_lds(
      (const __attribute__((address_space(1))) unsigned int*)g,
      (__attribute__((address_space(3))) unsigned int*)l, 16, 0, 0);
}

// ---------------- fp32 -> bf16 conversion (z selects source array) --------
__global__ __launch_bounds__(256) void cvt_kernel(
    const float* __restrict__ a0, const float* __restrict__ a1,
    const float* __restrict__ a2, const float* __restrict__ a3,
    unsigned short* __restrict__ out, int n_per) {
  const float* src = (blockIdx.z == 0) ? a0 : (blockIdx.z == 1) ? a1
                   : (blockIdx.z == 2) ? a2 : a3;
  unsigned short* dst = out + (size_t)blockIdx.z * n_per;
  int i = (blockIdx.x * 256 + threadIdx.x) * 8;
  if (i >= n_per) return;
  float4 x0 = *(const float4*)&src[i];
  float4 x1 = *(const float4*)&src[i + 4];
  alignas(16) unsigned short r[8] = {f2b(x0.x), f2b(x0.y), f2b(x0.z), f2b(x0.w),
                                     f2b(x1.x), f2b(x1.y), f2b(x1.z), f2b(x1.w)};
  *(uint4*)&dst[i] = *(const uint4*)r;
}

// ---------------- mask (int32 0/1) -> bitmask ----------------------------
__global__ __launch_bounds__(256) void pack_kernel(const int* __restrict__ m,
                                                   unsigned int* __restrict__ out) {
  size_t i = (size_t)blockIdx.x * 256 + threadIdx.x;
  unsigned long long w = __ballot(m[i] != 0);
  if ((threadIdx.x & 31) == 0)
    out[i >> 5] = (unsigned int)(w >> (threadIdx.x & 32));
}

// ---------- 128x128 bf16 GEMM, m97 structure + 3-bit chunk bank swizzle ---
// LDS slot sl of row r holds global 16B-chunk sl^(r&7)  (row stride 128 B
// aliases all rows to one bank group; the XOR spreads the 8 chunk slots
// across all 8 bank groups within each 16-lane phase -> conflict-free b128)
__device__ __forceinline__ void gemm128(
    const unsigned short* __restrict__ A, const unsigned short* __restrict__ W,
    const float* __restrict__ bias, float scale, int mode,
    unsigned short* __restrict__ outb, float* __restrict__ outf) {
  __shared__ unsigned short As[128 * 64];   // unpadded: global_load_lds dest
  __shared__ unsigned short Bs[128 * 64];
  const int m0 = blockIdx.x * 128;
  const int n0 = blockIdx.y * 128;
  const int t = threadIdx.x;
  const int lane = t & 63, wave = t >> 6;
  const int lr = lane & 15, quad = lane >> 4;
  const int wm = (wave >> 1) * 64, wn = (wave & 1) * 64;
  const int srow = (lane >> 3);               // within-chunk row 0..7
  const int scol = ((lane & 7) ^ srow) * 8;   // swizzled global col chunk
  // read-side swizzled chunk offsets (shorts), per-lane invariant
  const int cs0 = (quad ^ (lr & 7)) * 8;        // ks=0
  const int cs1 = ((4 + quad) ^ (lr & 7)) * 8;  // ks=1

  const f32x4 zv = {0.f, 0.f, 0.f, 0.f};
  f32x4 acc[4][4];
#pragma unroll
  for (int mt = 0; mt < 4; mt++)
#pragma unroll
    for (int nt = 0; nt < 4; nt++) acc[mt][nt] = zv;

  for (int kb = 0; kb < DM; kb += 64) {
    __syncthreads();
#pragma unroll
    for (int i = 0; i < 4; i++) {
      int c = wave * 4 + i;            // chunk of 8 rows (1 KB)
      int row = c * 8 + srow;
      gload_lds16(&A[(size_t)(m0 + row) * DM + kb + scol], &As[c * 512]);
      gload_lds16(&W[(size_t)(n0 + row) * DM + kb + scol], &Bs[c * 512]);
    }
    __syncthreads();
#pragma unroll
    for (int ks = 0; ks < 2; ks++) {
      const int cc = ks ? cs1 : cs0;
      short8 af[4], bf[4];
#pragma unroll
      for (int mt = 0; mt < 4; mt++)
        af[mt] = *(const short8*)&As[(wm + mt * 16 + lr) * 64 + cc];
#pragma unroll
      for (int nt = 0; nt < 4; nt++)
        bf[nt] = *(const short8*)&Bs[(wn + nt * 16 + lr) * 64 + cc];
#pragma unroll
      for (int mt = 0; mt < 4; mt++)
#pragma unroll
        for (int nt = 0; nt < 4; nt++)
          acc[mt][nt] = __builtin_amdgcn_mfma_f32_16x16x32_bf16(af[mt], bf[nt], acc[mt][nt], 0, 0, 0);
    }
  }

  // epilogue: C row = quad*4+reg, col = lr  (m89-verified C/D layout)
#pragma unroll
  for (int mt = 0; mt < 4; mt++) {
#pragma unroll
    for (int nt = 0; nt < 4; nt++) {
#pragma unroll
      for (int reg = 0; reg < 4; reg++) {
        int gm = m0 + wm + mt * 16 + quad * 4 + reg;
        int gn = n0 + wn + nt * 16 + lr;
        float v = (acc[mt][nt][reg] + bias[gn]) * scale;
        if (mode == 0) {        // bf16 [B,H,S,DK]
          int b = gm >> 11, s = gm & (S_ - 1);
          int h = gn >> 6, dk = gn & 63;
          outb[(((size_t)(b * H_ + h) * S_ + s) << 6) + dk] = f2b(v);
        } else if (mode == 1) { // bf16 [B,H,DK,S]  (V transposed)
          int b = gm >> 11, s = gm & (S_ - 1);
          int h = gn >> 6, dk = gn & 63;
          outb[(size_t)((b * H_ + h) * 64 + dk) * S_ + s] = f2b(v);
        } else {                // fp32 [B*S, DM]
          outf[(size_t)gm * DM + gn] = v;
        }
      }
    }
  }
}

__global__ __launch_bounds__(256) void gemm_qkv_kernel(
    const unsigned short* __restrict__ xb, const unsigned short* __restrict__ wb,
    const float* __restrict__ bq, const float* __restrict__ bk, const float* __restrict__ bv,
    unsigned short* __restrict__ q_out, unsigned short* __restrict__ k_out,
    unsigned short* __restrict__ v_out) {
  int z = blockIdx.z;
  const unsigned short* A = xb + (size_t)z * (B_ * S_ * DM);
  const unsigned short* W = wb + (size_t)z * (DM * DM);
  const float* bias = (z == 0) ? bq : (z == 1) ? bk : bv;
  unsigned short* ob = (z == 0) ? q_out : (z == 1) ? k_out : v_out;
  gemm128(A, W, bias, (z == 0) ? QSCALE : 1.0f, (z == 2) ? 1 : 0, ob, nullptr);
}

__global__ __launch_bounds__(256) void gemm_out_kernel(
    const unsigned short* __restrict__ ab, const unsigned short* __restrict__ wb,
    const float* __restrict__ bo, float* __restrict__ out) {
  gemm128(ab, wb + (size_t)3 * (DM * DM), bo, 1.0f, 2, nullptr, out);
}

// ------- flash attention v4: 3-bit bank swizzle + XCD-local grid ----------
// grid = (bh, qblock): the 16 q-blocks sharing one (b,h) have linear ids
// == bh (mod 8) -> same XCD -> K/V served from that XCD's L2.
__global__ __launch_bounds__(256, 4) void attn_kernel(
    const unsigned short* __restrict__ qb, const unsigned short* __restrict__ kb,
    const unsigned short* __restrict__ vt, const unsigned int* __restrict__ mbits,
    unsigned short* __restrict__ ao) {
  __shared__ unsigned short Ks[64 * 64];     // slot sl of row r holds chunk sl^(r&7)
  __shared__ unsigned short Vs[64 * 64];     // same swizzle, rows are d
  __shared__ unsigned short Pl[4][32 * 72];  // per-wave P buffer (C->A layout hop)
  const int bh = blockIdx.x;
  const int b = bh >> 4, h = bh & 15;
  const int t = threadIdx.x, lane = t & 63, wave = t >> 6;
  const int lr = lane & 15, quad = lane >> 4;
  const int q0 = blockIdx.y * 128 + wave * 32;  // wave owns 32 q-rows
  const unsigned short* qp = qb + (size_t)bh * S_ * DK;
  const unsigned short* kp = kb + (size_t)bh * S_ * DK;
  const unsigned short* vp = vt + (size_t)bh * DK * S_;
  const unsigned int* mrow = mbits + (size_t)b * S_ * (S_ / 32);
  unsigned short* plw = &Pl[wave][0];

  // staging: thread -> (row 0..31, slot t&7), fetches global chunk (t&7)^(row&7)
  const int trow = t >> 3;
  const int tsw = ((t & 7) ^ (trow & 7)) * 8;
  const int wbase = wave * 512;              // shorts; HW appends lane*16B
  // read-side swizzled chunk offsets (shorts)
  const int c0 = (quad ^ (lr & 7)) * 8;         // ks=0
  const int c1 = ((4 + quad) ^ (lr & 7)) * 8;   // ks=1
  const unsigned int sh0 = 31 - lr, sh1 = 15 - lr;  // mask bit -> sign extract

  short8 qf[2][2];
#pragma unroll
  for (int mt = 0; mt < 2; mt++)
#pragma unroll
    for (int ks = 0; ks < 2; ks++)
      qf[mt][ks] = *(const short8*)&qp[(size_t)(q0 + mt * 16 + lr) * DK + ks * 32 + quad * 8];

  const f32x4 zv = {0.f, 0.f, 0.f, 0.f};
  short8 ones;
#pragma unroll
  for (int i = 0; i < 8; i++) ones[i] = (short)0x3F80;  // bf16 1.0
  f32x4 oacc[2][4], lacc[2];
#pragma unroll
  for (int mt = 0; mt < 2; mt++) {
    lacc[mt] = zv;
#pragma unroll
    for (int nt = 0; nt < 4; nt++) oacc[mt][nt] = zv;
  }

  for (int kt = 0; kt < S_ / 64; kt++) {
    const int kbase = kt * 64;
    // mask prefetch (latency overlaps the staging barrier + vmcnt drain)
    uint2 mw[2][4];
#pragma unroll
    for (int mt = 0; mt < 2; mt++)
#pragma unroll
      for (int r = 0; r < 4; r++)
        mw[mt][r] = *(const uint2*)&mrow[(size_t)(q0 + mt * 16 + quad * 4 + r) * (S_ / 32) + kt * 2];

    __syncthreads();  // all waves done reading previous Ks/Vs
    gload_lds16(kp + (size_t)(kbase + trow) * DK + tsw,      &Ks[wbase]);
    gload_lds16(kp + (size_t)(kbase + 32 + trow) * DK + tsw, &Ks[2048 + wbase]);
    gload_lds16(vp + (size_t)trow * S_ + kbase + tsw,        &Vs[wbase]);
    gload_lds16(vp + (size_t)(32 + trow) * S_ + kbase + tsw, &Vs[2048 + wbase]);
    __syncthreads();  // staging visible

    // ---- S = Q K^T (exp2 domain; scale folded into Q)
    f32x4 sacc[2][4];
#pragma unroll
    for (int nt = 0; nt < 4; nt++) {
      short8 kf0 = *(const short8*)&Ks[(nt * 16 + lr) * 64 + c0];
      short8 kf1 = *(const short8*)&Ks[(nt * 16 + lr) * 64 + c1];
#pragma unroll
      for (int mt = 0; mt < 2; mt++) {
        f32x4 z = __builtin_amdgcn_mfma_f32_16x16x32_bf16(qf[mt][0], kf0, zv, 0, 0, 0);
        sacc[mt][nt] = __builtin_amdgcn_mfma_f32_16x16x32_bf16(qf[mt][1], kf1, z, 0, 0, 0);
      }
    }
    // ---- p = exp2(s) & maskbit -> per-wave LDS (C-layout rows)
#pragma unroll
    for (int mt = 0; mt < 2; mt++) {
#pragma unroll
      for (int r = 0; r < 4; r++) {
        uint2 m2 = mw[mt][r];
#pragma unroll
        for (int nt = 0; nt < 4; nt++) {
          unsigned int w = (nt < 2) ? m2.x : m2.y;
          unsigned int shl = (nt & 1) ? sh1 : sh0;
          float e = exp2f(sacc[mt][nt][r]);
          unsigned int pb = (__float_as_uint(e) + 0x8000u) >> 16;  // round-half-up bf16
          pb &= (unsigned int)(((int)(w << shl)) >> 31);           // 0 or all-ones
          plw[(mt * 16 + quad * 4 + r) * 72 + nt * 16 + lr] = (unsigned short)pb;
        }
      }
    }
    // wave-local LDS RAW: compiler lgkmcnt, no barrier needed
    short8 pf[2][2];
#pragma unroll
    for (int mt = 0; mt < 2; mt++)
#pragma unroll
      for (int ks = 0; ks < 2; ks++)
        pf[mt][ks] = *(const short8*)&plw[(mt * 16 + lr) * 72 + ks * 32 + quad * 8];
    // ---- l += P @ 1
#pragma unroll
    for (int mt = 0; mt < 2; mt++) {
      lacc[mt] = __builtin_amdgcn_mfma_f32_16x16x32_bf16(pf[mt][0], ones, lacc[mt], 0, 0, 0);
      lacc[mt] = __builtin_amdgcn_mfma_f32_16x16x32_bf16(pf[mt][1], ones, lacc[mt], 0, 0, 0);
    }
    // ---- O += P V   (Vs rows are d, cols key-in-tile, swizzled)
#pragma unroll
    for (int nt = 0; nt < 4; nt++) {
      short8 vf0 = *(const short8*)&Vs[(nt * 16 + lr) * 64 + c0];
      short8 vf1 = *(const short8*)&Vs[(nt * 16 + lr) * 64 + c1];
#pragma unroll
      for (int mt = 0; mt < 2; mt++) {
        oacc[mt][nt] = __builtin_amdgcn_mfma_f32_16x16x32_bf16(pf[mt][0], vf0, oacc[mt][nt], 0, 0, 0);
        oacc[mt][nt] = __builtin_amdgcn_mfma_f32_16x16x32_bf16(pf[mt][1], vf1, oacc[mt][nt], 0, 0, 0);
      }
    }
  }
  // ---- epilogue: O/l -> bf16 [B, S, H*DK]; fully-masked row -> 0
#pragma unroll
  for (int mt = 0; mt < 2; mt++) {
#pragma unroll
    for (int r = 0; r < 4; r++) {
      float l = lacc[mt][r];
      float inv = (l > 0.f) ? 1.f / l : 0.f;
      int row = q0 + mt * 16 + quad * 4 + r;
#pragma unroll
      for (int nt = 0; nt < 4; nt++)
        ao[((size_t)(b * S_ + row) * DM) + h * 64 + nt * 16 + lr] =
            f2b(oacc[mt][nt][r] * inv);
    }
  }
}

extern "C" void kernel_launch(void* const* d_in, const int* in_sizes, int n_in,
                              void* d_out, int out_size, void* d_ws, size_t ws_size,
                              hipStream_t stream) {
  const float* query = (const float*)d_in[0];
  const float* key   = (const float*)d_in[1];
  const float* value = (const float*)d_in[2];
  const int*   mask  = (const int*)d_in[3];
  const float* Wq = (const float*)d_in[4];
  const float* bq = (const float*)d_in[5];
  const float* Wk = (const float*)d_in[6];
  const float* bk = (const float*)d_in[7];
  const float* Wv = (const float*)d_in[8];
  const float* bv = (const float*)d_in[9];
  const float* Wo = (const float*)d_in[10];
  const float* bo = (const float*)d_in[11];
  float* out = (float*)d_out;
  char* ws = (char*)d_ws;

  // workspace layout (bytes)
  unsigned short* qb = (unsigned short*)(ws);                 // 16.78 MB [B,H,S,DK] (pre-scaled)
  unsigned short* kbf = (unsigned short*)(ws + 16777216);     // 16.78 MB [B,H,S,DK]
  unsigned short* vt = (unsigned short*)(ws + 33554432);      // 16.78 MB [B,H,DK,S]
  unsigned short* wb = (unsigned short*)(ws + 50331648);      // 8.39 MB  4x[DM,DM]
  unsigned int*   mb = (unsigned int*)(ws + 58720256);        // 2.10 MB  bits
  unsigned short* xb = (unsigned short*)(ws + 60817408);      // 50.33 MB bf16 q,k,v inputs
  unsigned short* ao = (unsigned short*)(ws + 60817408);      // alias: reused after QKV GEMM

  cvt_kernel<<<dim3(4096, 1, 3), 256, 0, stream>>>(query, key, value, nullptr, xb, B_ * S_ * DM);
  cvt_kernel<<<dim3(512, 1, 4), 256, 0, stream>>>(Wq, Wk, Wv, Wo, wb, DM * DM);
  pack_kernel<<<dim3(65536), 256, 0, stream>>>(mask, mb);
  gemm_qkv_kernel<<<dim3(64, 8, 3), 256, 0, stream>>>(xb, wb, bq, bk, bv, qb, kbf, vt);
  attn_kernel<<<dim3(64, 16), 256, 0, stream>>>(qb, kbf, vt, mb, ao);
  gemm_out_kernel<<<dim3(64, 8), 256, 0, stream>>>(ao, wb, bo, out);
}

// Round 5
// 444.083 us; speedup vs baseline: 1.8116x; 1.0637x over previous
//
#include <hip/hip_runtime.h>

typedef __attribute__((ext_vector_type(8))) short short8;
typedef __attribute__((ext_vector_type(4))) float f32x4;

#define B_ 4
#define S_ 2048
#define H_ 16
#define DM 1024
#define DK 64

// 0.125 * log2(e): folds the 1/sqrt(64) score scale + exp->exp2 conversion into Q
#define QSCALE 0.18033688011112042f

__device__ __forceinline__ unsigned short f2b(float f) {
  unsigned int u = __float_as_uint(f);
  u += 0x7fff + ((u >> 16) & 1);   // RNE
  return (unsigned short)(u >> 16);
}

__device__ __forceinline__ void gload_lds16(const void* g, void* l) {
  __builtin_amdgcn_global_load_lds(
      (const __attribute__((address_space(1))) unsigned int*)g,
      (__attribute__((address_space(3))) unsigned int*)l, 16, 0, 0);
}

// ---------------- fp32 -> bf16 conversion (z selects source array) --------
__global__ __launch_bounds__(256) void cvt_kernel(
    const float* __restrict__ a0, const float* __restrict__ a1,
    const float* __restrict__ a2, const float* __restrict__ a3,
    unsigned short* __restrict__ out, int n_per) {
  const float* src = (blockIdx.z == 0) ? a0 : (blockIdx.z == 1) ? a1
                   : (blockIdx.z == 2) ? a2 : a3;
  unsigned short* dst = out + (size_t)blockIdx.z * n_per;
  int i = (blockIdx.x * 256 + threadIdx.x) * 8;
  if (i >= n_per) return;
  float4 x0 = *(const float4*)&src[i];
  float4 x1 = *(const float4*)&src[i + 4];
  alignas(16) unsigned short r[8] = {f2b(x0.x), f2b(x0.y), f2b(x0.z), f2b(x0.w),
                                     f2b(x1.x), f2b(x1.y), f2b(x1.z), f2b(x1.w)};
  *(uint4*)&dst[i] = *(const uint4*)r;
}

// ---------------- mask (int32 0/1) -> bitmask ----------------------------
__global__ __launch_bounds__(256) void pack_kernel(const int* __restrict__ m,
                                                   unsigned int* __restrict__ out) {
  size_t i = (size_t)blockIdx.x * 256 + threadIdx.x;
  unsigned long long w = __ballot(m[i] != 0);
  if ((threadIdx.x & 31) == 0)
    out[i >> 5] = (unsigned int)(w >> (threadIdx.x & 32));
}

// ---------- 128x128 bf16 GEMM, m97 structure + 3-bit chunk bank swizzle ---
// LDS slot sl of row r holds global 16B-chunk sl^(r&7).
// mode 1 (V^T output) routes the tile through an LDS transpose so global
// stores are coalesced dwordx4 runs along s (was a stride-2048 b16 scatter).
__device__ __forceinline__ void gemm128(
    const unsigned short* __restrict__ A, const unsigned short* __restrict__ W,
    const float* __restrict__ bias, float scale, int mode,
    unsigned short* __restrict__ outb, float* __restrict__ outf) {
  __shared__ unsigned short Sh[128 * 132];  // As(16KB) + Bs(16KB); mode1: Ts stride 132
  unsigned short* As = Sh;
  unsigned short* Bs = Sh + 128 * 64;
  const int m0 = blockIdx.x * 128;
  const int n0 = blockIdx.y * 128;
  const int t = threadIdx.x;
  const int lane = t & 63, wave = t >> 6;
  const int lr = lane & 15, quad = lane >> 4;
  const int wm = (wave >> 1) * 64, wn = (wave & 1) * 64;
  const int srow = (lane >> 3);               // within-chunk row 0..7
  const int scol = ((lane & 7) ^ srow) * 8;   // swizzled global col chunk
  // read-side swizzled chunk offsets (shorts), per-lane invariant
  const int cs0 = (quad ^ (lr & 7)) * 8;        // ks=0
  const int cs1 = ((4 + quad) ^ (lr & 7)) * 8;  // ks=1

  const f32x4 zv = {0.f, 0.f, 0.f, 0.f};
  f32x4 acc[4][4];
#pragma unroll
  for (int mt = 0; mt < 4; mt++)
#pragma unroll
    for (int nt = 0; nt < 4; nt++) acc[mt][nt] = zv;

  for (int kb = 0; kb < DM; kb += 64) {
    __syncthreads();
#pragma unroll
    for (int i = 0; i < 4; i++) {
      int c = wave * 4 + i;            // chunk of 8 rows (1 KB)
      int row = c * 8 + srow;
      gload_lds16(&A[(size_t)(m0 + row) * DM + kb + scol], &As[c * 512]);
      gload_lds16(&W[(size_t)(n0 + row) * DM + kb + scol], &Bs[c * 512]);
    }
    __syncthreads();
#pragma unroll
    for (int ks = 0; ks < 2; ks++) {
      const int cc = ks ? cs1 : cs0;
      short8 af[4], bf[4];
#pragma unroll
      for (int mt = 0; mt < 4; mt++)
        af[mt] = *(const short8*)&As[(wm + mt * 16 + lr) * 64 + cc];
#pragma unroll
      for (int nt = 0; nt < 4; nt++)
        bf[nt] = *(const short8*)&Bs[(wn + nt * 16 + lr) * 64 + cc];
#pragma unroll
      for (int mt = 0; mt < 4; mt++)
#pragma unroll
        for (int nt = 0; nt < 4; nt++)
          acc[mt][nt] = __builtin_amdgcn_mfma_f32_16x16x32_bf16(af[mt], bf[nt], acc[mt][nt], 0, 0, 0);
    }
  }

  if (mode == 1) {
    // ---- LDS transpose epilogue: Ts[n][m], stride 132 (conflict-free) ----
    __syncthreads();   // all waves done reading As/Bs before overwrite
#pragma unroll
    for (int mt = 0; mt < 4; mt++) {
#pragma unroll
      for (int nt = 0; nt < 4; nt++) {
        int n = wn + nt * 16 + lr;
        int m = wm + mt * 16 + quad * 4;
        float bn = bias[n0 + n];
        alignas(8) unsigned short p4[4];
#pragma unroll
        for (int reg = 0; reg < 4; reg++)
          p4[reg] = f2b((acc[mt][nt][reg] + bn) * scale);
        *(uint2*)&Sh[n * 132 + m] = *(const uint2*)p4;
      }
    }
    __syncthreads();
    // copy out: thread t -> output row n = t>>1, m-half = (t&1)*64
    int n = t >> 1, mh = (t & 1) * 64;
    int gn = n0 + n;
    int h = gn >> 6, dk = gn & 63;
    int b = m0 >> 11, s0 = (m0 & (S_ - 1)) + mh;
    size_t obase = (size_t)((b * H_ + h) * 64 + dk) * S_ + s0;
#pragma unroll
    for (int c = 0; c < 8; c++)
      *(uint4*)&outb[obase + c * 8] = *(const uint4*)&Sh[n * 132 + mh + c * 8];
    return;
  }

  // epilogue (modes 0,2): C row = quad*4+reg, col = lr
#pragma unroll
  for (int mt = 0; mt < 4; mt++) {
#pragma unroll
    for (int nt = 0; nt < 4; nt++) {
#pragma unroll
      for (int reg = 0; reg < 4; reg++) {
        int gm = m0 + wm + mt * 16 + quad * 4 + reg;
        int gn = n0 + wn + nt * 16 + lr;
        float v = (acc[mt][nt][reg] + bias[gn]) * scale;
        if (mode == 0) {        // bf16 [B,H,S,DK]
          int b = gm >> 11, s = gm & (S_ - 1);
          int h = gn >> 6, dk = gn & 63;
          outb[(((size_t)(b * H_ + h) * S_ + s) << 6) + dk] = f2b(v);
        } else {                // fp32 [B*S, DM]
          outf[(size_t)gm * DM + gn] = v;
        }
      }
    }
  }
}

__global__ __launch_bounds__(256) void gemm_qkv_kernel(
    const unsigned short* __restrict__ xb, const unsigned short* __restrict__ wb,
    const float* __restrict__ bq, const float* __restrict__ bk, const float* __restrict__ bv,
    unsigned short* __restrict__ q_out, unsigned short* __restrict__ k_out,
    unsigned short* __restrict__ v_out) {
  int z = blockIdx.z;
  const unsigned short* A = xb + (size_t)z * (B_ * S_ * DM);
  const unsigned short* W = wb + (size_t)z * (DM * DM);
  const float* bias = (z == 0) ? bq : (z == 1) ? bk : bv;
  unsigned short* ob = (z == 0) ? q_out : (z == 1) ? k_out : v_out;
  gemm128(A, W, bias, (z == 0) ? QSCALE : 1.0f, (z == 2) ? 1 : 0, ob, nullptr);
}

__global__ __launch_bounds__(256) void gemm_out_kernel(
    const unsigned short* __restrict__ ab, const unsigned short* __restrict__ wb,
    const float* __restrict__ bo, float* __restrict__ out) {
  gemm128(ab, wb + (size_t)3 * (DM * DM), bo, 1.0f, 2, nullptr, out);
}

// ------- flash attention v5: double-buffered K/V staging, 1 barrier/kt ----
__global__ __launch_bounds__(256, 3) void attn_kernel(
    const unsigned short* __restrict__ qb, const unsigned short* __restrict__ kb,
    const unsigned short* __restrict__ vt, const unsigned int* __restrict__ mbits,
    unsigned short* __restrict__ ao) {
  __shared__ unsigned short Ks[2][64 * 64];  // slot sl of row r holds chunk sl^(r&7)
  __shared__ unsigned short Vs[2][64 * 64];  // same swizzle, rows are d
  __shared__ unsigned short Pl[4][32 * 72];  // per-wave P buffer (C->A layout hop)
  const int bh = blockIdx.x;
  const int b = bh >> 4, h = bh & 15;
  const int t = threadIdx.x, lane = t & 63, wave = t >> 6;
  const int lr = lane & 15, quad = lane >> 4;
  const int q0 = blockIdx.y * 128 + wave * 32;  // wave owns 32 q-rows
  const unsigned short* qp = qb + (size_t)bh * S_ * DK;
  const unsigned short* kp = kb + (size_t)bh * S_ * DK;
  const unsigned short* vp = vt + (size_t)bh * DK * S_;
  const unsigned int* mrow = mbits + (size_t)b * S_ * (S_ / 32);
  unsigned short* plw = &Pl[wave][0];

  // staging: thread -> (row 0..31, slot t&7), fetches global chunk (t&7)^(row&7)
  const int trow = t >> 3;
  const int tsw = ((t & 7) ^ (trow & 7)) * 8;
  const int wbase = wave * 512;              // shorts; HW appends lane*16B
  // read-side swizzled chunk offsets (shorts)
  const int c0 = (quad ^ (lr & 7)) * 8;         // ks=0
  const int c1 = ((4 + quad) ^ (lr & 7)) * 8;   // ks=1
  const unsigned int sh0 = 31 - lr, sh1 = 15 - lr;  // mask bit -> sign extract

  short8 qf[2][2];
#pragma unroll
  for (int mt = 0; mt < 2; mt++)
#pragma unroll
    for (int ks = 0; ks < 2; ks++)
      qf[mt][ks] = *(const short8*)&qp[(size_t)(q0 + mt * 16 + lr) * DK + ks * 32 + quad * 8];

  const f32x4 zv = {0.f, 0.f, 0.f, 0.f};
  short8 ones;
#pragma unroll
  for (int i = 0; i < 8; i++) ones[i] = (short)0x3F80;  // bf16 1.0
  f32x4 oacc[2][4], lacc[2];
#pragma unroll
  for (int mt = 0; mt < 2; mt++) {
    lacc[mt] = zv;
#pragma unroll
    for (int nt = 0; nt < 4; nt++) oacc[mt][nt] = zv;
  }

#define STAGE(KT, BUF) do {                                                   \
    int kb2 = (KT) * 64;                                                      \
    gload_lds16(kp + (size_t)(kb2 + trow) * DK + tsw,      &Ks[BUF][wbase]);  \
    gload_lds16(kp + (size_t)(kb2 + 32 + trow) * DK + tsw, &Ks[BUF][2048 + wbase]); \
    gload_lds16(vp + (size_t)trow * S_ + kb2 + tsw,        &Vs[BUF][wbase]);  \
    gload_lds16(vp + (size_t)(32 + trow) * S_ + kb2 + tsw, &Vs[BUF][2048 + wbase]); \
  } while (0)

  auto body = [&](int kt, int buf) {
    // mask loads first: overlap with QK^T compute
    uint2 mw[2][4];
#pragma unroll
    for (int mt = 0; mt < 2; mt++)
#pragma unroll
      for (int r = 0; r < 4; r++)
        mw[mt][r] = *(const uint2*)&mrow[(size_t)(q0 + mt * 16 + quad * 4 + r) * (S_ / 32) + kt * 2];

    // ---- S = Q K^T (exp2 domain; scale folded into Q)
    f32x4 sacc[2][4];
#pragma unroll
    for (int nt = 0; nt < 4; nt++) {
      short8 kf0 = *(const short8*)&Ks[buf][(nt * 16 + lr) * 64 + c0];
      short8 kf1 = *(const short8*)&Ks[buf][(nt * 16 + lr) * 64 + c1];
#pragma unroll
      for (int mt = 0; mt < 2; mt++) {
        f32x4 z = __builtin_amdgcn_mfma_f32_16x16x32_bf16(qf[mt][0], kf0, zv, 0, 0, 0);
        sacc[mt][nt] = __builtin_amdgcn_mfma_f32_16x16x32_bf16(qf[mt][1], kf1, z, 0, 0, 0);
      }
    }
    // ---- p = exp2(s) & maskbit -> per-wave LDS (C-layout rows)
#pragma unroll
    for (int mt = 0; mt < 2; mt++) {
#pragma unroll
      for (int r = 0; r < 4; r++) {
        uint2 m2 = mw[mt][r];
#pragma unroll
        for (int nt = 0; nt < 4; nt++) {
          unsigned int w = (nt < 2) ? m2.x : m2.y;
          unsigned int shl = (nt & 1) ? sh1 : sh0;
          float e = exp2f(sacc[mt][nt][r]);
          unsigned int pb = (__float_as_uint(e) + 0x8000u) >> 16;  // round-half-up bf16
          pb &= (unsigned int)(((int)(w << shl)) >> 31);           // 0 or all-ones
          plw[(mt * 16 + quad * 4 + r) * 72 + nt * 16 + lr] = (unsigned short)pb;
        }
      }
    }
    // wave-local LDS RAW: compiler lgkmcnt, no barrier needed
    short8 pf[2][2];
#pragma unroll
    for (int mt = 0; mt < 2; mt++)
#pragma unroll
      for (int ks = 0; ks < 2; ks++)
        pf[mt][ks] = *(const short8*)&plw[(mt * 16 + lr) * 72 + ks * 32 + quad * 8];
    // ---- l += P @ 1
#pragma unroll
    for (int mt = 0; mt < 2; mt++) {
      lacc[mt] = __builtin_amdgcn_mfma_f32_16x16x32_bf16(pf[mt][0], ones, lacc[mt], 0, 0, 0);
      lacc[mt] = __builtin_amdgcn_mfma_f32_16x16x32_bf16(pf[mt][1], ones, lacc[mt], 0, 0, 0);
    }
    // ---- O += P V   (Vs rows are d, cols key-in-tile, swizzled)
#pragma unroll
    for (int nt = 0; nt < 4; nt++) {
      short8 vf0 = *(const short8*)&Vs[buf][(nt * 16 + lr) * 64 + c0];
      short8 vf1 = *(const short8*)&Vs[buf][(nt * 16 + lr) * 64 + c1];
#pragma unroll
      for (int mt = 0; mt < 2; mt++) {
        oacc[mt][nt] = __builtin_amdgcn_mfma_f32_16x16x32_bf16(pf[mt][0], vf0, oacc[mt][nt], 0, 0, 0);
        oacc[mt][nt] = __builtin_amdgcn_mfma_f32_16x16x32_bf16(pf[mt][1], vf1, oacc[mt][nt], 0, 0, 0);
      }
    }
  };

  STAGE(0, 0);
  for (int kt = 0; kt < S_ / 64; kt += 2) {
    __syncthreads();              // buf0 staged & prior readers of buf0 done
    STAGE(kt + 1, 1);             // prefetch next tile into buf1 (async)
    body(kt, 0);
    __syncthreads();              // buf1 staged & prior readers of buf1 done
    if (kt + 2 < S_ / 64) STAGE(kt + 2, 0);
    body(kt + 1, 1);
  }
#undef STAGE

  // ---- epilogue: O/l -> bf16 [B, S, H*DK]; fully-masked row -> 0
#pragma unroll
  for (int mt = 0; mt < 2; mt++) {
#pragma unroll
    for (int r = 0; r < 4; r++) {
      float l = lacc[mt][r];
      float inv = (l > 0.f) ? 1.f / l : 0.f;
      int row = q0 + mt * 16 + quad * 4 + r;
#pragma unroll
      for (int nt = 0; nt < 4; nt++)
        ao[((size_t)(b * S_ + row) * DM) + h * 64 + nt * 16 + lr] =
            f2b(oacc[mt][nt][r] * inv);
    }
  }
}

extern "C" void kernel_launch(void* const* d_in, const int* in_sizes, int n_in,
                              void* d_out, int out_size, void* d_ws, size_t ws_size,
                              hipStream_t stream) {
  const float* query = (const float*)d_in[0];
  const float* key   = (const float*)d_in[1];
  const float* value = (const float*)d_in[2];
  const int*   mask  = (const int*)d_in[3];
  const float* Wq = (const float*)d_in[4];
  const float* bq = (const float*)d_in[5];
  const float* Wk = (const float*)d_in[6];
  const float* bk = (const float*)d_in[7];
  const float* Wv = (const float*)d_in[8];
  const float* bv = (const float*)d_in[9];
  const float* Wo = (const float*)d_in[10];
  const float* bo = (const float*)d_in[11];
  float* out = (float*)d_out;
  char* ws = (char*)d_ws;

  // workspace layout (bytes)
  unsigned short* qb = (unsigned short*)(ws);                 // 16.78 MB [B,H,S,DK] (pre-scaled)
  unsigned short* kbf = (unsigned short*)(ws + 16777216);     // 16.78 MB [B,H,S,DK]
  unsigned short* vt = (unsigned short*)(ws + 33554432);      // 16.78 MB [B,H,DK,S]
  unsigned short* wb = (unsigned short*)(ws + 50331648);      // 8.39 MB  4x[DM,DM]
  unsigned int*   mb = (unsigned int*)(ws + 58720256);        // 2.10 MB  bits
  unsigned short* xb = (unsigned short*)(ws + 60817408);      // 50.33 MB bf16 q,k,v inputs
  unsigned short* ao = (unsigned short*)(ws + 60817408);      // alias: reused after QKV GEMM

  cvt_kernel<<<dim3(4096, 1, 3), 256, 0, stream>>>(query, key, value, nullptr, xb, B_ * S_ * DM);
  cvt_kernel<<<dim3(512, 1, 4), 256, 0, stream>>>(Wq, Wk, Wv, Wo, wb, DM * DM);
  pack_kernel<<<dim3(65536), 256, 0, stream>>>(mask, mb);
  gemm_qkv_kernel<<<dim3(64, 8, 3), 256, 0, stream>>>(xb, wb, bq, bk, bv, qb, kbf, vt);
  attn_kernel<<<dim3(64, 16), 256, 0, stream>>>(qb, kbf, vt, mb, ao);
  gemm_out_kernel<<<dim3(64, 8), 256, 0, stream>>>(ao, wb, bo, out);
}